// Round 5
// baseline (124.214 us; speedup 1.0000x reference)
//
#include <hip/hip_runtime.h>
#include <math.h>

#define HW1 (1024 * 1024)
#define WID 1024
#define HEI 1024

// ws layout (floats): acc[64] | pool[24*65536] | cosbuf[1024*1024]
#define POOL_OFF   64
#define POOL_FLTS  (24 * 65536)
#define COS_OFF    (POOL_OFF + POOL_FLTS)

// Block-level reduce (wave shfl + LDS) then one atomicAdd per block.
__device__ __forceinline__ void block_atomic_add(float v, float* target, volatile float* sdata) {
#pragma unroll
    for (int off = 32; off > 0; off >>= 1)
        v += __shfl_down(v, off, 64);
    const int lane = threadIdx.x & 63;
    const int wv   = threadIdx.x >> 6;
    if (lane == 0) sdata[wv] = v;
    __syncthreads();
    if (threadIdx.x == 0) {
        float s = 0.f;
        const int nw = blockDim.x >> 6;
        for (int i = 0; i < nw; ++i) s += sdata[i];
        atomicAdd(target, s);
    }
    __syncthreads();
}

// Kernel A.
// Blocks [0,1536): main pass, one (pool-row gy, channel c, half-row h) each.
//   Linear-burst streaming: per batch b, a wave reads 2x1KB consecutive chunks
//   of A and of B (one plane each) -> long sequential runs, batch-major sweep.
// Blocks [1536,2304): Sobel s_loss on batch-0 planes.
__global__ __launch_bounds__(256) void k_A(const float* __restrict__ A,
                                           const float* __restrict__ B,
                                           float* __restrict__ ws) {
    __shared__ float pdl[8 * 4 * 128];   // [b][yl][cell], cell = k*64+xl
    __shared__ float s1[4];

    float* acc    = ws;
    float* pool   = ws + POOL_OFF;
    float* cosbuf = ws + COS_OFF;

    const int tid = threadIdx.x;

    if (blockIdx.x < 1536) {
        const int m  = blockIdx.x;
        const int gy = m / 6;            // pool-y 0..255
        const int r6 = m % 6;
        const int c  = r6 >> 1;          // channel 0..2
        const int h  = r6 & 1;           // half-row 0..1
        const int xl = tid & 63;
        const int yl = tid >> 6;         // row within pool cell
        const int y  = gy * 4 + yl;

        const float4* A4 = reinterpret_cast<const float4*>(A);
        const float4* B4 = reinterpret_cast<const float4*>(B);
        // float4 base index of this row's half: row y, columns [h*512, h*512+512)
        const int rbase = y * 256 + h * 128;

        float na2[8], nb2[8], dt[8];     // 8 pixels: k in {0,1} x 4 lanes of float4
#pragma unroll
        for (int i = 0; i < 8; ++i) { na2[i] = 0.f; nb2[i] = 0.f; dt[i] = 0.f; }
        float r_sum = 0.f;

#pragma unroll
        for (int b = 0; b < 8; ++b) {
            const int pbase = (b * 3 + c) * (HW1 / 4) + rbase;
            // 4 loads: two consecutive 1KB chunks of A, same of B (linear bursts)
            const float4 a0 = A4[pbase + xl];
            const float4 a1 = A4[pbase + 64 + xl];
            const float4 b0 = B4[pbase + xl];
            const float4 b1 = B4[pbase + 64 + xl];

            float pd0 = 0.f, pd1 = 0.f;
            {
                const float a = a0.x, t = b0.x;
                na2[0] += a * a; nb2[0] += t * t; dt[0] += a * t;
                r_sum += fabsf(a - t); pd0 += t - a;
            }
            {
                const float a = a0.y, t = b0.y;
                na2[1] += a * a; nb2[1] += t * t; dt[1] += a * t;
                r_sum += fabsf(a - t); pd0 += t - a;
            }
            {
                const float a = a0.z, t = b0.z;
                na2[2] += a * a; nb2[2] += t * t; dt[2] += a * t;
                r_sum += fabsf(a - t); pd0 += t - a;
            }
            {
                const float a = a0.w, t = b0.w;
                na2[3] += a * a; nb2[3] += t * t; dt[3] += a * t;
                r_sum += fabsf(a - t); pd0 += t - a;
            }
            {
                const float a = a1.x, t = b1.x;
                na2[4] += a * a; nb2[4] += t * t; dt[4] += a * t;
                r_sum += fabsf(a - t); pd1 += t - a;
            }
            {
                const float a = a1.y, t = b1.y;
                na2[5] += a * a; nb2[5] += t * t; dt[5] += a * t;
                r_sum += fabsf(a - t); pd1 += t - a;
            }
            {
                const float a = a1.z, t = b1.z;
                na2[6] += a * a; nb2[6] += t * t; dt[6] += a * t;
                r_sum += fabsf(a - t); pd1 += t - a;
            }
            {
                const float a = a1.w, t = b1.w;
                na2[7] += a * a; nb2[7] += t * t; dt[7] += a * t;
                r_sum += fabsf(a - t); pd1 += t - a;
            }
            pdl[(b * 4 + yl) * 128 + xl]      = pd0;
            pdl[(b * 4 + yl) * 128 + 64 + xl] = pd1;
        }

        // per-pixel channel cos component -> atomic accumulate into cosbuf
#pragma unroll
        for (int k = 0; k < 2; ++k) {
#pragma unroll
            for (int j = 0; j < 4; ++j) {
                const int i  = k * 4 + j;
                const float na = fmaxf(sqrtf(na2[i]), 1e-12f);
                const float nb = fmaxf(sqrtf(nb2[i]), 1e-12f);
                const float f  = dt[i] / (na * nb);
                // pixel x = (h*128 + k*64 + xl)*4 + j ; linear idx = y*1024 + x
                atomicAdd(&cosbuf[(size_t)(rbase + k * 64 + xl) * 4 + j], f);
            }
        }

        __syncthreads();
        // pool reduce: 8 b x 128 cells, 4 per thread
#pragma unroll
        for (int i = 0; i < 4; ++i) {
            const int s    = i * 256 + tid;
            const int b    = s >> 7;
            const int cell = s & 127;
            const float v = pdl[(b * 4 + 0) * 128 + cell] + pdl[(b * 4 + 1) * 128 + cell]
                          + pdl[(b * 4 + 2) * 128 + cell] + pdl[(b * 4 + 3) * 128 + cell];
            pool[(size_t)(b * 3 + c) * 65536 + gy * 256 + h * 128 + cell] = v * (1.0f / 16.0f);
        }

        block_atomic_add(r_sum, acc + 0, s1);
    } else {
        // ---------------- Sobel path: 4x4 output tile per thread ----------------
        const int t   = (blockIdx.x - 1536) * 256 + tid;  // 0 .. 196607
        const int qx  = t & 255;
        const int rem = t >> 8;
        const int qy  = rem & 255;
        const int c   = rem >> 8;
        const int x0  = qx * 4;
        const int y0  = qy * 4;

        const float* Ap = A + (size_t)c * HW1;
        const float* Bp = B + (size_t)c * HW1;

        float rd[6][4];  // rowdiff(y,x) = d(y,x-1) - d(y,x+1), rows y0-1..y0+4
#pragma unroll
        for (int r = 0; r < 6; ++r) {
            const int yy = y0 - 1 + r;
            if (yy < 0 || yy >= HEI) {
                rd[r][0] = rd[r][1] = rd[r][2] = rd[r][3] = 0.f;
                continue;
            }
            const float* ap = Ap + (size_t)yy * WID;
            const float* bp = Bp + (size_t)yy * WID;
            const float4 a4 = *reinterpret_cast<const float4*>(ap + x0);
            const float4 b4 = *reinterpret_cast<const float4*>(bp + x0);
            const float dm = (qx > 0)   ? (ap[x0 - 1] - bp[x0 - 1]) : 0.f;
            const float dp = (qx < 255) ? (ap[x0 + 4] - bp[x0 + 4]) : 0.f;
            const float d0 = a4.x - b4.x;
            const float d1 = a4.y - b4.y;
            const float d2 = a4.z - b4.z;
            const float d3 = a4.w - b4.w;
            rd[r][0] = dm - d1;
            rd[r][1] = d0 - d2;
            rd[r][2] = d1 - d3;
            rd[r][3] = d2 - dp;
        }

        float s = 0.f;
#pragma unroll
        for (int o = 0; o < 4; ++o) {
#pragma unroll
            for (int i = 0; i < 4; ++i)
                s += fabsf(rd[o][i] + 2.f * rd[o + 1][i] + rd[o + 2][i]);
        }

        block_atomic_add(s, acc + 2, s1);
    }
}

// Kernel B. Blocks [0,1024): cos finalize (clip + acos + reduce).
// Blocks [1024,3072): spatial-consistency loss from pool.
__global__ __launch_bounds__(256) void k_B(float* __restrict__ ws) {
    __shared__ float sd[4];
    float* acc    = ws;
    float* pool   = ws + POOL_OFF;
    float* cosbuf = ws + COS_OFF;

    const int tid = threadIdx.x;

    if (blockIdx.x < 1024) {
        const int t = blockIdx.x * 256 + tid;   // float4 index 0 .. 262143
        const float4 cv = reinterpret_cast<const float4*>(cosbuf)[t];
        float c_sum = 0.f;
        const float lo = -1.0f + 1e-7f, hi = 1.0f - 1e-7f;
        c_sum += acosf(fminf(fmaxf(cv.x, lo), hi));
        c_sum += acosf(fminf(fmaxf(cv.y, lo), hi));
        c_sum += acosf(fminf(fmaxf(cv.z, lo), hi));
        c_sum += acosf(fminf(fmaxf(cv.w, lo), hi));
        block_atomic_add(c_sum, acc + 1, sd);
    } else {
        const int t = (blockIdx.x - 1024) * 256 + tid;  // 0 .. 524287
        const int x = t & 255;
        const int y = (t >> 8) & 255;
        const int b = t >> 16;

        const float* Rr = pool + (size_t)(b * 3 + 0) * 65536 + y * 256;
        const float* Gg = pool + (size_t)(b * 3 + 1) * 65536 + y * 256;
        const float* Bb = pool + (size_t)(b * 3 + 2) * 65536 + y * 256;

        const float g  = Gg[x];
        const float gl = (x > 0)   ? Gg[x - 1] : 0.f;
        const float gr = (x < 255) ? Gg[x + 1] : 0.f;
        const float d0 = g - gl;
        const float d1 = g - gr;
        const float d2 = g - Rr[x];
        const float d3 = g - Bb[x];
        const float s  = d0 * d0 + d1 * d1 + d2 * d2 + d3 * d3;

        block_atomic_add(s, acc + 3, sd);
    }
}

// Combine: out = W_C*c + W_R*r + W_P*p + W_S*s
__global__ void k_final(const float* __restrict__ acc, float* __restrict__ out) {
    const float r = acc[0] * (1.0f / 25165824.0f);  // mean over 8*3*1024*1024
    const float c = acc[1];
    const float s = acc[2];
    const float p = acc[3] * (1.0f / 524288.0f);    // mean over 8*256*256
    out[0] = 0.5f * c + 1.0f * r + 1.0f * p + 0.1f * s;
}

extern "C" void kernel_launch(void* const* d_in, const int* in_sizes, int n_in,
                              void* d_out, int out_size, void* d_ws, size_t ws_size,
                              hipStream_t stream) {
    const float* A = (const float*)d_in[0];  // predictions
    const float* B = (const float*)d_in[1];  // targets
    float* ws = (float*)d_ws;

    hipMemsetAsync(ws, 0, 64 * sizeof(float), stream);                       // acc
    hipMemsetAsync(ws + COS_OFF, 0, (size_t)HW1 * sizeof(float), stream);    // cosbuf

    hipLaunchKernelGGL(k_A,     dim3(2304), dim3(256), 0, stream, A, B, ws);
    hipLaunchKernelGGL(k_B,     dim3(3072), dim3(256), 0, stream, ws);
    hipLaunchKernelGGL(k_final, dim3(1),    dim3(1),   0, stream, ws, (float*)d_out);
}